// Round 13
// baseline (507.673 us; speedup 1.0000x reference)
//
#include <hip/hip_runtime.h>
#include <math.h>

#define BB 4
#define TT 12
#define NN 2000
#define CC 8
#define HH 64
#define EE 32000
#define NHEADS 8
#define HD 8
#define HORZ 12
#define BT (BB*TT)        // 48
#define RR (BT*NN)        // 96000 rows of H=64

using bf16x8 = __attribute__((ext_vector_type(8))) __bf16;
using f16x8  = __attribute__((ext_vector_type(8))) _Float16;
using f16x4  = __attribute__((ext_vector_type(4))) _Float16;
using f32x4  = __attribute__((ext_vector_type(4))) float;

__device__ __forceinline__ float sigmoidf_(float x){ return 1.0f/(1.0f+__expf(-x)); }
__device__ __forceinline__ float siluf_(float x){ return x/(1.0f+__expf(-x)); }

// ================= CSR build (edges sorted by tgt) =================
__global__ void k_hist(const int* __restrict__ eidx, int* __restrict__ cnt) {
    int e = blockIdx.x*blockDim.x + threadIdx.x;
    if (e < EE) atomicAdd(&cnt[eidx[EE + e]], 1);
}

__global__ __launch_bounds__(256) void k_scan(const int* __restrict__ cnt,
                                              int* __restrict__ ofs_work) {
    __shared__ int part[256];
    int tid = threadIdx.x;
    int local[8]; int s = 0;
    #pragma unroll
    for (int k = 0; k < 8; ++k) {
        int idx = tid*8 + k;
        int v = (idx < NN) ? cnt[idx] : 0;
        local[k] = s; s += v;
    }
    part[tid] = s; __syncthreads();
    for (int off = 1; off < 256; off <<= 1) {
        int v = part[tid];
        int u = (tid >= off) ? part[tid-off] : 0;
        __syncthreads();
        part[tid] = v + u;
        __syncthreads();
    }
    int excl = part[tid] - s;
    #pragma unroll
    for (int k = 0; k < 8; ++k) {
        int idx = tid*8 + k;
        if (idx < NN) ofs_work[idx] = excl + local[k];
    }
}

__global__ void k_scatter(const int* __restrict__ eidx, int* __restrict__ ofs_work,
                          int* __restrict__ ssrc, int* __restrict__ stgt) {
    int e = blockIdx.x*blockDim.x + threadIdx.x;
    if (e >= EE) return;
    int t = eidx[EE + e];
    int pos = atomicAdd(&ofs_work[t], 1);
    ssrc[pos] = eidx[e];
    stgt[pos] = t;
}

// ========== one-shot weight prep: transposed [n][k] low-precision copies ==
__global__ void k_wprep(
    const float* __restrict__ mw2_0, const float* __restrict__ mw2_1,
    const float* __restrict__ uw1_0, const float* __restrict__ uw1_1,
    const float* __restrict__ uw2_0, const float* __restrict__ uw2_1,
    const float* __restrict__ wq, const float* __restrict__ wk,
    const float* __restrict__ wv, const float* __restrict__ wo,
    const float* __restrict__ mw1_0, const float* __restrict__ mw1_1,
    const float* __restrict__ up_w,
    __bf16* __restrict__ mw2t0, __bf16* __restrict__ mw2t1,
    _Float16* __restrict__ uw1t0, _Float16* __restrict__ uw1t1,
    _Float16* __restrict__ uw2t0, _Float16* __restrict__ uw2t1,
    _Float16* __restrict__ qkvt, _Float16* __restrict__ wot,
    _Float16* __restrict__ mw1t0, _Float16* __restrict__ mw1t1,
    _Float16* __restrict__ upwt)
{
    int i = blockIdx.x*blockDim.x + threadIdx.x;
    if (i < 2048) {
        int n = i >> 5, k = i & 31;
        mw2t0[i] = (__bf16)mw2_0[k*64 + n];
        mw2t1[i] = (__bf16)mw2_1[k*64 + n];
        return;
    }
    i -= 2048;
    if (i < 8192) {
        int n = i >> 7, k = i & 127;
        uw1t0[i] = (_Float16)uw1_0[k*64 + n];
        uw1t1[i] = (_Float16)uw1_1[k*64 + n];
        return;
    }
    i -= 8192;
    if (i < 4096) {
        int n = i >> 6, k = i & 63;
        uw2t0[i] = (_Float16)uw2_0[k*64 + n];
        uw2t1[i] = (_Float16)uw2_1[k*64 + n];
        wot[i]   = (_Float16)wo[k*64 + n];
        qkvt[i]        = (_Float16)wq[k*64 + n];
        qkvt[4096 + i] = (_Float16)wk[k*64 + n];
        qkvt[8192 + i] = (_Float16)wv[k*64 + n];
        mw1t0[i] = (_Float16)((n < 32) ? mw1_0[k*32 + n] : mw1_0[(64 + k)*32 + n - 32]);
        mw1t1[i] = (_Float16)((n < 32) ? mw1_1[k*32 + n] : mw1_1[(64 + k)*32 + n - 32]);
        return;
    }
    i -= 4096;
    if (i < 2048) {
        int n = i >> 5, k = i & 31;
        upwt[i] = (k < CC) ? (_Float16)up_w[k*64 + n] : (_Float16)0.0f;
    }
}

// ====== MFMA helpers: 32-row tile per wave, A direct from global f32 ======
__device__ __forceinline__ f16x8 load_a_f16(const float* __restrict__ p) {
    f32x4 lo = *(const f32x4*)p, hi = *(const f32x4*)(p + 4);
    f16x8 v;
    #pragma unroll
    for (int u = 0; u < 4; ++u) { v[u] = (_Float16)lo[u]; v[4+u] = (_Float16)hi[u]; }
    return v;
}

// ------- fused up-projection (MFMA, K=8 padded) + sp1 msg-layer-1 pre ----
__global__ __launch_bounds__(64) void k_upre(
    const float* __restrict__ x, const _Float16* __restrict__ upwt,
    const float* __restrict__ upb, const _Float16* __restrict__ mw1t,
    float* __restrict__ h, _Float16* __restrict__ preB)
{
    __shared__ _Float16 hS[32][72];
    int t = threadIdx.x; int l15 = t & 15, quad = t >> 4;
    size_t R0 = (size_t)blockIdx.x*32;

    f16x8 a[2];
    #pragma unroll
    for (int mi = 0; mi < 2; ++mi) {
        f16x8 v;
        #pragma unroll
        for (int u = 0; u < 8; ++u) v[u] = (_Float16)0.0f;
        if (quad == 0) {
            const float* xr = x + (R0 + 16*mi + l15)*CC;
            f32x4 lo = *(const f32x4*)xr, hi = *(const f32x4*)(xr + 4);
            #pragma unroll
            for (int u = 0; u < 4; ++u) { v[u] = (_Float16)lo[u]; v[4+u] = (_Float16)hi[u]; }
        }
        a[mi] = v;
    }
    f32x4 acc[2][4];
    #pragma unroll
    for (int mi = 0; mi < 2; ++mi)
        #pragma unroll
        for (int ni = 0; ni < 4; ++ni) acc[mi][ni] = (f32x4){0.f,0.f,0.f,0.f};
    #pragma unroll
    for (int ni = 0; ni < 4; ++ni) {
        f16x8 b = *(const f16x8*)&upwt[(16*ni + l15)*32 + quad*8];
        #pragma unroll
        for (int mi = 0; mi < 2; ++mi)
            acc[mi][ni] = __builtin_amdgcn_mfma_f32_16x16x32_f16(a[mi], b, acc[mi][ni], 0,0,0);
    }
    #pragma unroll
    for (int mi = 0; mi < 2; ++mi)
        #pragma unroll
        for (int ni = 0; ni < 4; ++ni) {
            int col = 16*ni + l15;
            float bb = upb[col];
            #pragma unroll
            for (int rg = 0; rg < 4; ++rg) {
                int row = 16*mi + 4*quad + rg;
                float o = fmaxf(acc[mi][ni][rg] + bb, 0.f);
                h[(R0 + row)*HH + col] = o;
                hS[row][col] = (_Float16)o;
            }
        }
    __syncthreads();

    f32x4 acc2[2][4];
    #pragma unroll
    for (int mi = 0; mi < 2; ++mi)
        #pragma unroll
        for (int ni = 0; ni < 4; ++ni) acc2[mi][ni] = (f32x4){0.f,0.f,0.f,0.f};
    #pragma unroll
    for (int kc = 0; kc < 2; ++kc) {
        f16x8 av[2];
        #pragma unroll
        for (int mi = 0; mi < 2; ++mi)
            av[mi] = *(const f16x8*)&hS[16*mi + l15][kc*32 + quad*8];
        #pragma unroll
        for (int ni = 0; ni < 4; ++ni) {
            f16x8 b = *(const f16x8*)&mw1t[(16*ni + l15)*64 + kc*32 + quad*8];
            #pragma unroll
            for (int mi = 0; mi < 2; ++mi)
                acc2[mi][ni] = __builtin_amdgcn_mfma_f32_16x16x32_f16(av[mi], b, acc2[mi][ni], 0,0,0);
        }
    }
    #pragma unroll
    for (int mi = 0; mi < 2; ++mi)
        #pragma unroll
        for (int ni = 0; ni < 4; ++ni) {
            int col = 16*ni + l15;
            #pragma unroll
            for (int rg = 0; rg < 4; ++rg) {
                int row = 16*mi + 4*quad + rg;
                preB[(R0 + row)*HH + col] = (_Float16)acc2[mi][ni][rg];
            }
        }
}

// ------- fused update-MLP(sp1) + QKV: h2 never hits global; QKV f16 ------
__global__ __launch_bounds__(64) void k_updqkv(
    const float* __restrict__ agg, const float* __restrict__ h,
    const _Float16* __restrict__ w1t, const float* __restrict__ b1,
    const _Float16* __restrict__ w2t, const float* __restrict__ b2,
    const _Float16* __restrict__ qkvt,
    const float* __restrict__ bq, const float* __restrict__ bk,
    const float* __restrict__ bv,
    _Float16* __restrict__ q, _Float16* __restrict__ k, _Float16* __restrict__ v)
{
    __shared__ _Float16 uS[32][72];
    __shared__ _Float16 hS[32][72];
    int t = threadIdx.x; int l15 = t & 15, quad = t >> 4;
    size_t R0 = (size_t)blockIdx.x*32;

    f32x4 acc[2][4];
    #pragma unroll
    for (int mi = 0; mi < 2; ++mi)
        #pragma unroll
        for (int ni = 0; ni < 4; ++ni) acc[mi][ni] = (f32x4){0.f,0.f,0.f,0.f};
    #pragma unroll
    for (int kc = 0; kc < 4; ++kc) {
        const float* src = (kc < 2) ? agg : h;
        int colb = (kc & 1)*32 + quad*8;
        f16x8 a[2];
        #pragma unroll
        for (int mi = 0; mi < 2; ++mi)
            a[mi] = load_a_f16(src + (R0 + 16*mi + l15)*HH + colb);
        #pragma unroll
        for (int ni = 0; ni < 4; ++ni) {
            f16x8 b = *(const f16x8*)&w1t[(16*ni + l15)*128 + kc*32 + quad*8];
            #pragma unroll
            for (int mi = 0; mi < 2; ++mi)
                acc[mi][ni] = __builtin_amdgcn_mfma_f32_16x16x32_f16(a[mi], b, acc[mi][ni], 0,0,0);
        }
    }
    #pragma unroll
    for (int mi = 0; mi < 2; ++mi)
        #pragma unroll
        for (int ni = 0; ni < 4; ++ni) {
            int col = 16*ni + l15;
            float bb = b1[col];
            #pragma unroll
            for (int rg = 0; rg < 4; ++rg)
                uS[16*mi + 4*quad + rg][col] = (_Float16)siluf_(acc[mi][ni][rg] + bb);
        }
    __syncthreads();

    f32x4 acc2[2][4];
    #pragma unroll
    for (int mi = 0; mi < 2; ++mi)
        #pragma unroll
        for (int ni = 0; ni < 4; ++ni) acc2[mi][ni] = (f32x4){0.f,0.f,0.f,0.f};
    #pragma unroll
    for (int kc = 0; kc < 2; ++kc) {
        f16x8 a[2];
        #pragma unroll
        for (int mi = 0; mi < 2; ++mi)
            a[mi] = *(const f16x8*)&uS[16*mi + l15][kc*32 + quad*8];
        #pragma unroll
        for (int ni = 0; ni < 4; ++ni) {
            f16x8 b = *(const f16x8*)&w2t[(16*ni + l15)*64 + kc*32 + quad*8];
            #pragma unroll
            for (int mi = 0; mi < 2; ++mi)
                acc2[mi][ni] = __builtin_amdgcn_mfma_f32_16x16x32_f16(a[mi], b, acc2[mi][ni], 0,0,0);
        }
    }
    #pragma unroll
    for (int mi = 0; mi < 2; ++mi)
        #pragma unroll
        for (int ni = 0; ni < 4; ++ni) {
            int col = 16*ni + l15;
            float bb = b2[col];
            #pragma unroll
            for (int rg = 0; rg < 4; ++rg) {
                int row = 16*mi + 4*quad + rg;
                float o = acc2[mi][ni][rg] + bb + h[(R0 + row)*HH + col];
                hS[row][col] = (_Float16)fmaxf(o, 0.f);
            }
        }
    __syncthreads();

    f16x8 a[2][2];
    #pragma unroll
    for (int kc = 0; kc < 2; ++kc)
        #pragma unroll
        for (int mi = 0; mi < 2; ++mi)
            a[kc][mi] = *(const f16x8*)&hS[16*mi + l15][kc*32 + quad*8];

    const float* bias[3] = {bq, bk, bv};
    _Float16* outp[3] = {q, k, v};
    #pragma unroll
    for (int o = 0; o < 3; ++o) {
        f32x4 ac[2][4];
        #pragma unroll
        for (int mi = 0; mi < 2; ++mi)
            #pragma unroll
            for (int ni = 0; ni < 4; ++ni) ac[mi][ni] = (f32x4){0.f,0.f,0.f,0.f};
        #pragma unroll
        for (int kc = 0; kc < 2; ++kc)
            #pragma unroll
            for (int ni = 0; ni < 4; ++ni) {
                f16x8 b = *(const f16x8*)&qkvt[o*4096 + (16*ni + l15)*64 + kc*32 + quad*8];
                #pragma unroll
                for (int mi = 0; mi < 2; ++mi)
                    ac[mi][ni] = __builtin_amdgcn_mfma_f32_16x16x32_f16(a[kc][mi], b, ac[mi][ni], 0,0,0);
            }
        #pragma unroll
        for (int mi = 0; mi < 2; ++mi)
            #pragma unroll
            for (int ni = 0; ni < 4; ++ni) {
                int col = 16*ni + l15;
                float bb = bias[o][col];
                #pragma unroll
                for (int rg = 0; rg < 4; ++rg) {
                    int row = 16*mi + 4*quad + rg;
                    outp[o][(R0 + row)*HH + col] = (_Float16)(ac[mi][ni][rg] + bb);
                }
            }
    }
}

// ------- MFMA update MLP (sp2): f16 output for the conv head -------------
__global__ __launch_bounds__(64) void k_updm(
    const float* __restrict__ agg, const float* __restrict__ h,
    const _Float16* __restrict__ w1t, const float* __restrict__ b1,
    const _Float16* __restrict__ w2t, const float* __restrict__ b2,
    _Float16* __restrict__ out)
{
    __shared__ _Float16 uS[32][72];
    int t = threadIdx.x; int l15 = t & 15, quad = t >> 4;
    size_t R0 = (size_t)blockIdx.x*32;

    f32x4 acc[2][4];
    #pragma unroll
    for (int mi = 0; mi < 2; ++mi)
        #pragma unroll
        for (int ni = 0; ni < 4; ++ni) acc[mi][ni] = (f32x4){0.f,0.f,0.f,0.f};
    #pragma unroll
    for (int kc = 0; kc < 4; ++kc) {
        const float* src = (kc < 2) ? agg : h;
        int colb = (kc & 1)*32 + quad*8;
        f16x8 a[2];
        #pragma unroll
        for (int mi = 0; mi < 2; ++mi)
            a[mi] = load_a_f16(src + (R0 + 16*mi + l15)*HH + colb);
        #pragma unroll
        for (int ni = 0; ni < 4; ++ni) {
            f16x8 b = *(const f16x8*)&w1t[(16*ni + l15)*128 + kc*32 + quad*8];
            #pragma unroll
            for (int mi = 0; mi < 2; ++mi)
                acc[mi][ni] = __builtin_amdgcn_mfma_f32_16x16x32_f16(a[mi], b, acc[mi][ni], 0,0,0);
        }
    }
    #pragma unroll
    for (int mi = 0; mi < 2; ++mi)
        #pragma unroll
        for (int ni = 0; ni < 4; ++ni) {
            int col = 16*ni + l15;
            float bb = b1[col];
            #pragma unroll
            for (int rg = 0; rg < 4; ++rg)
                uS[16*mi + 4*quad + rg][col] = (_Float16)siluf_(acc[mi][ni][rg] + bb);
        }
    __syncthreads();

    f32x4 acc2[2][4];
    #pragma unroll
    for (int mi = 0; mi < 2; ++mi)
        #pragma unroll
        for (int ni = 0; ni < 4; ++ni) acc2[mi][ni] = (f32x4){0.f,0.f,0.f,0.f};
    #pragma unroll
    for (int kc = 0; kc < 2; ++kc) {
        f16x8 a[2];
        #pragma unroll
        for (int mi = 0; mi < 2; ++mi)
            a[mi] = *(const f16x8*)&uS[16*mi + l15][kc*32 + quad*8];
        #pragma unroll
        for (int ni = 0; ni < 4; ++ni) {
            f16x8 b = *(const f16x8*)&w2t[(16*ni + l15)*64 + kc*32 + quad*8];
            #pragma unroll
            for (int mi = 0; mi < 2; ++mi)
                acc2[mi][ni] = __builtin_amdgcn_mfma_f32_16x16x32_f16(a[mi], b, acc2[mi][ni], 0,0,0);
        }
    }
    #pragma unroll
    for (int mi = 0; mi < 2; ++mi)
        #pragma unroll
        for (int ni = 0; ni < 4; ++ni) {
            int col = 16*ni + l15;
            float bb = b2[col];
            #pragma unroll
            for (int rg = 0; rg < 4; ++rg) {
                int row = 16*mi + 4*quad + rg;
                float o = acc2[mi][ni][rg] + bb + h[(R0 + row)*HH + col];
                out[(R0 + row)*HH + col] = (_Float16)fmaxf(o, 0.f);
            }
        }
}

// ------- MFMA Wo projection (f16 in) + fused sp2 msg-layer-1 pre ---------
__global__ __launch_bounds__(64) void k_wopre(
    const _Float16* __restrict__ ob, const _Float16* __restrict__ wot,
    const float* __restrict__ bo, const _Float16* __restrict__ mw1t,
    float* __restrict__ aout, _Float16* __restrict__ preB)
{
    __shared__ _Float16 hS[32][72];
    int t = threadIdx.x; int l15 = t & 15, quad = t >> 4;
    size_t R0 = (size_t)blockIdx.x*32;

    f32x4 acc[2][4];
    #pragma unroll
    for (int mi = 0; mi < 2; ++mi)
        #pragma unroll
        for (int ni = 0; ni < 4; ++ni) acc[mi][ni] = (f32x4){0.f,0.f,0.f,0.f};
    #pragma unroll
    for (int kc = 0; kc < 2; ++kc) {
        f16x8 a[2];
        #pragma unroll
        for (int mi = 0; mi < 2; ++mi)
            a[mi] = *(const f16x8*)&ob[(R0 + 16*mi + l15)*HH + kc*32 + quad*8];
        #pragma unroll
        for (int ni = 0; ni < 4; ++ni) {
            f16x8 b = *(const f16x8*)&wot[(16*ni + l15)*64 + kc*32 + quad*8];
            #pragma unroll
            for (int mi = 0; mi < 2; ++mi)
                acc[mi][ni] = __builtin_amdgcn_mfma_f32_16x16x32_f16(a[mi], b, acc[mi][ni], 0,0,0);
        }
    }
    #pragma unroll
    for (int mi = 0; mi < 2; ++mi)
        #pragma unroll
        for (int ni = 0; ni < 4; ++ni) {
            int col = 16*ni + l15;
            float bb = bo[col];
            #pragma unroll
            for (int rg = 0; rg < 4; ++rg) {
                int row = 16*mi + 4*quad + rg;
                float o = acc[mi][ni][rg] + bb;
                aout[(R0 + row)*HH + col] = o;
                hS[row][col] = (_Float16)o;
            }
        }
    __syncthreads();

    f32x4 acc2[2][4];
    #pragma unroll
    for (int mi = 0; mi < 2; ++mi)
        #pragma unroll
        for (int ni = 0; ni < 4; ++ni) acc2[mi][ni] = (f32x4){0.f,0.f,0.f,0.f};
    #pragma unroll
    for (int kc = 0; kc < 2; ++kc) {
        f16x8 a[2];
        #pragma unroll
        for (int mi = 0; mi < 2; ++mi)
            a[mi] = *(const f16x8*)&hS[16*mi + l15][kc*32 + quad*8];
        #pragma unroll
        for (int ni = 0; ni < 4; ++ni) {
            f16x8 b = *(const f16x8*)&mw1t[(16*ni + l15)*64 + kc*32 + quad*8];
            #pragma unroll
            for (int mi = 0; mi < 2; ++mi)
                acc2[mi][ni] = __builtin_amdgcn_mfma_f32_16x16x32_f16(a[mi], b, acc2[mi][ni], 0,0,0);
        }
    }
    #pragma unroll
    for (int mi = 0; mi < 2; ++mi)
        #pragma unroll
        for (int ni = 0; ni < 4; ++ni) {
            int col = 16*ni + l15;
            #pragma unroll
            for (int rg = 0; rg < 4; ++rg) {
                int row = 16*mi + 4*quad + rg;
                preB[(R0 + row)*HH + col] = (_Float16)acc2[mi][ni][rg];
            }
        }
}

// ========== message MLP + gate + indicator-MFMA segmented aggregation =====
// blockIdx = eb*BT + bt -> all 500 windows of a bt land on XCD bt%8.
__global__ __launch_bounds__(64) void k_msg(
    const _Float16* __restrict__ preB, const int* __restrict__ ssrc,
    const int* __restrict__ stgt,
    const float* __restrict__ b1,
    const __bf16* __restrict__ w2t, const float* __restrict__ b2,
    const float* __restrict__ gw, const float* __restrict__ gb,
    float* __restrict__ agg)
{
    int bt = blockIdx.x % BT;          // XCD-local per bt
    int eb = blockIdx.x / BT;
    int t  = threadIdx.x;
    int l15 = t & 15, quad = t >> 4;

    union __align__(16) SM {
        __bf16   ab[64][40];
        _Float16 bs[8][64][8];
    };
    __shared__ SM sm;
    __shared__ int segTgt[64];

    int e0 = eb*64;
    int my_src = ssrc[e0 + t];
    int my_tgt = stgt[e0 + t];

    int prevt = __shfl(my_tgt, (t + 63) & 63);
    bool bnd = (t == 0) || (prevt != my_tgt);
    unsigned long long bm = __ballot(bnd);
    int seg = __builtin_amdgcn_mbcnt_hi((unsigned)(bm >> 32),
              __builtin_amdgcn_mbcnt_lo((unsigned)bm, 0u));
    int nseg = __popcll(bm);
    if (bnd) segTgt[seg] = my_tgt;

    const _Float16* basep = preB + (size_t)bt*NN*HH;
    const _Float16* rT = basep + (size_t)my_tgt*HH;
    const _Float16* rS = basep + (size_t)my_src*HH + 32;
    f16x8 xi[4], xj[4];
    #pragma unroll
    for (int g4 = 0; g4 < 4; ++g4) {
        xi[g4] = *(const f16x8*)&rT[8*g4];
        xj[g4] = *(const f16x8*)&rS[8*g4];
    }
    #pragma unroll
    for (int g4 = 0; g4 < 4; ++g4) {
        bf16x8 v;
        #pragma unroll
        for (int u = 0; u < 8; ++u) {
            float m = (float)xi[g4][u] + (float)xj[g4][u] + b1[8*g4 + u];
            v[u] = (__bf16)siluf_(m);
        }
        ((bf16x8*)&sm.ab[t][0])[g4] = v;
    }

    bf16x8 bfr[4];
    float b2v[4], gwv[4];
    #pragma unroll
    for (int ni = 0; ni < 4; ++ni) {
        bfr[ni] = *(const bf16x8*)&w2t[(16*ni + l15)*32 + quad*8];
        b2v[ni] = b2[16*ni + l15];
        gwv[ni] = gw[16*ni + l15];
    }
    float gb0 = gb[0];

    __syncthreads();

    f32x4 acc[4][4];
    #pragma unroll
    for (int mi = 0; mi < 4; ++mi) {
        bf16x8 af = *(const bf16x8*)&sm.ab[16*mi + l15][quad*8];
        #pragma unroll
        for (int ni = 0; ni < 4; ++ni) {
            f32x4 z = {0.f, 0.f, 0.f, 0.f};
            acc[mi][ni] = __builtin_amdgcn_mfma_f32_16x16x32_bf16(af, bfr[ni], z, 0, 0, 0);
        }
    }
    __syncthreads();

    #pragma unroll
    for (int mi = 0; mi < 4; ++mi) {
        float sv[4][4];
        #pragma unroll
        for (int ni = 0; ni < 4; ++ni)
            #pragma unroll
            for (int rg = 0; rg < 4; ++rg)
                sv[ni][rg] = siluf_(acc[mi][ni][rg] + b2v[ni]);
        float gg[4];
        #pragma unroll
        for (int rg = 0; rg < 4; ++rg) {
            float p = sv[0][rg]*gwv[0] + sv[1][rg]*gwv[1]
                    + sv[2][rg]*gwv[2] + sv[3][rg]*gwv[3];
            p += __shfl_xor(p, 1); p += __shfl_xor(p, 2);
            p += __shfl_xor(p, 4); p += __shfl_xor(p, 8);
            gg[rg] = sigmoidf_(p + gb0);
        }
        int c  = mi >> 1;
        int qb = 2*(mi & 1) + (quad >> 1);
        int j0 = 4*(quad & 1);
        #pragma unroll
        for (int ni = 0; ni < 4; ++ni) {
            f16x4 pk;
            #pragma unroll
            for (int rg = 0; rg < 4; ++rg) pk[rg] = (_Float16)(sv[ni][rg]*gg[rg]);
            *(f16x4*)&sm.bs[c*4 + ni][16*qb + l15][j0] = pk;
        }
    }
    __syncthreads();

    f16x8 bfrag[2][4];
    #pragma unroll
    for (int c = 0; c < 2; ++c)
        #pragma unroll
        for (int ni = 0; ni < 4; ++ni)
            bfrag[c][ni] = *(const f16x8*)&sm.bs[c*4 + ni][t][0];

    float* ap = agg + (size_t)bt*NN*HH;
    for (int g0 = 0; g0 < nseg; g0 += 16) {
        f16x8 ind[2];
        #pragma unroll
        for (int c = 0; c < 2; ++c) {
            #pragma unroll
            for (int j = 0; j < 8; ++j) {
                int sj = __shfl(seg, 32*c + 8*quad + j);
                ind[c][j] = (sj == g0 + l15) ? (_Float16)1.0f : (_Float16)0.0f;
            }
        }
        f32x4 av[4];
        #pragma unroll
        for (int ni = 0; ni < 4; ++ni) {
            f32x4 z = {0.f, 0.f, 0.f, 0.f};
            av[ni] = __builtin_amdgcn_mfma_f32_16x16x32_f16(ind[0], bfrag[0][ni], z, 0, 0, 0);
            av[ni] = __builtin_amdgcn_mfma_f32_16x16x32_f16(ind[1], bfrag[1][ni], av[ni], 0, 0, 0);
        }
        #pragma unroll
        for (int rg = 0; rg < 4; ++rg) {
            int s = g0 + 4*quad + rg;
            if (s < nseg) {
                int tn = segTgt[s];
                #pragma unroll
                for (int ni = 0; ni < 4; ++ni)
                    atomicAdd(&ap[(size_t)tn*HH + 16*ni + l15], av[ni][rg]);
            }
        }
    }
}

// ---------------- temporal attention: f16 in/out, f32 compute -------------
__global__ __launch_bounds__(64) void k_attn2(
    const _Float16* __restrict__ q, const _Float16* __restrict__ k,
    const _Float16* __restrict__ v, _Float16* __restrict__ o)
{
    __shared__ float Qs[TT][68], Ks[TT][68], Vs[TT][68], Os[TT][68];
    int p = blockIdx.x;
    int b = p / NN, n = p % NN;
    int j = threadIdx.x;
    const size_t stride = (size_t)NN*HH;
    const size_t base0  = ((size_t)(b*TT)*NN + n)*HH;

    #pragma unroll
    for (int t = 0; t < TT; ++t) {
        size_t off = base0 + (size_t)t*stride + j;
        Qs[t][j] = (float)q[off];
        Ks[t][j] = (float)k[off];
        Vs[t][j] = (float)v[off];
    }
    __syncthreads();

    #pragma unroll
    for (int half = 0; half < 2; ++half) {
        if (j < 48) {
            int head = half*4 + j/12;
            int s    = j % 12;
            f32x4 qv0 = *(const f32x4*)&Qs[s][head*8];
            f32x4 qv1 = *(const f32x4*)&Qs[s][head*8 + 4];
            float sc[TT]; float mx = -1e30f;
            #pragma unroll
            for (int t = 0; t < TT; ++t) {
                f32x4 k0 = *(const f32x4*)&Ks[t][head*8];
                f32x4 k1 = *(const f32x4*)&Ks[t][head*8 + 4];
                float a = qv0[0]*k0[0] + qv0[1]*k0[1] + qv0[2]*k0[2] + qv0[3]*k0[3]
                        + qv1[0]*k1[0] + qv1[1]*k1[1] + qv1[2]*k1[2] + qv1[3]*k1[3];
                a *= 0.35355339059327373f;
                sc[t] = a; mx = fmaxf(mx, a);
            }
            float sum = 0.f;
            #pragma unroll
            for (int t = 0; t < TT; ++t) { sc[t] = __expf(sc[t]-mx); sum += sc[t]; }
            float inv = 1.0f/sum;
            f32x4 o0 = {0.f,0.f,0.f,0.f}, o1 = {0.f,0.f,0.f,0.f};
            #pragma unroll
            for (int t = 0; t < TT; ++t) {
                float a = sc[t]*inv;
                f32x4 v0 = *(const f32x4*)&Vs[t][head*8];
                f32x4 v1 = *(const f32x4*)&Vs[t][head*8 + 4];
                o0[0]+=a*v0[0]; o0[1]+=a*v0[1]; o0[2]+=a*v0[2]; o0[3]+=a*v0[3];
                o1[0]+=a*v1[0]; o1[1]+=a*v1[1]; o1[2]+=a*v1[2]; o1[3]+=a*v1[3];
            }
            *(f32x4*)&Os[s][head*8]     = o0;
            *(f32x4*)&Os[s][head*8 + 4] = o1;
        }
    }
    __syncthreads();

    #pragma unroll
    for (int t = 0; t < TT; ++t)
        o[base0 + (size_t)t*stride + j] = (_Float16)Os[t][j];
}

// ---------------- conv head stage 1: z f16 [b,hor,n,0:72] -----------------
__global__ __launch_bounds__(256) void k_zbuild(
    const _Float16* __restrict__ h, const float* __restrict__ x,
    const float* __restrict__ cw, const float* __restrict__ cb,
    _Float16* __restrict__ z)
{
    int gid = blockIdx.x*blockDim.x + threadIdx.x;
    int p = gid >> 6;
    int j = gid & 63;
    if (p >= BB*NN) return;
    p = __builtin_amdgcn_readfirstlane(p);
    int b = p / NN, n = p % NN;

    float hv[TT];
    #pragma unroll
    for (int t = 0; t < TT; ++t)
        hv[t] = (float)h[((size_t)(b*TT + t)*NN + n)*HH + j];
    float xv[TT];
    if (j < CC) {
        #pragma unroll
        for (int t = 0; t < TT; ++t)
            xv[t] = x[((size_t)(b*TT + t)*NN + n)*CC + j];
    }

    #pragma unroll
    for (int hor = 0; hor < HORZ; ++hor) {
        float cbv = cb[hor];
        float zh = cbv, zx = cbv;
        #pragma unroll
        for (int t = 0; t < TT; ++t) {
            float w = cw[hor*TT + t];
            zh += w*hv[t];
            if (j < CC) zx += w*xv[t];
        }
        size_t row = (size_t)(b*HORZ + hor)*NN + n;
        z[row*72 + j] = (_Float16)zh;
        if (j < CC) z[row*72 + 64 + j] = (_Float16)zx;
    }
}

// ---------------- conv head stage 2: out = relu(z@w1+b1)@w2+b2 ------------
__global__ __launch_bounds__(256) void k_headmlp(
    const _Float16* __restrict__ z,
    const float* __restrict__ w1, const float* __restrict__ b1,
    const float* __restrict__ w2, const float* __restrict__ b2,
    float* __restrict__ out)
{
    __shared__ float U[4][4][65];
    int gid = blockIdx.x*blockDim.x + threadIdx.x;
    int wv_ = gid >> 6; int j = gid & 63;
    int wl = threadIdx.x >> 6;
    int r0 = wv_*4;
    r0 = __builtin_amdgcn_readfirstlane(r0);
    const _Float16* zr = z + (size_t)r0*72;
    float bj = b1[j];
    float a0=bj,a1=bj,a2=bj,a3=bj;
    #pragma unroll 8
    for (int c = 0; c < 72; ++c) {
        float wc = w1[c*64 + j];
        a0 += (float)zr[c]*wc;      a1 += (float)zr[72+c]*wc;
        a2 += (float)zr[144+c]*wc;  a3 += (float)zr[216+c]*wc;
    }
    U[wl][0][j] = fmaxf(a0, 0.f);
    U[wl][1][j] = fmaxf(a1, 0.f);
    U[wl][2][j] = fmaxf(a2, 0.f);
    U[wl][3][j] = fmaxf(a3, 0.f);
    __syncthreads();

    if (j < 32) {
        int r = j >> 3, c = j & 7;
        float o = b2[c];
        #pragma unroll 8
        for (int k = 0; k < 64; ++k)
            o += U[wl][r][k] * w2[k*8 + c];
        out[(size_t)(r0 + r)*CC + c] = o;
    }
}

extern "C" void kernel_launch(void* const* d_in, const int* in_sizes, int n_in,
                              void* d_out, int out_size, void* d_ws, size_t ws_size,
                              hipStream_t stream) {
    const float* x    = (const float*)d_in[0];
    const int*   eidx = (const int*)d_in[1];
    const float* up_w = (const float*)d_in[2];
    const float* up_b = (const float*)d_in[3];
    const float* sp_w[2][10];
    for (int p = 0; p < 2; ++p)
        for (int i = 0; i < 10; ++i)
            sp_w[p][i] = (const float*)d_in[4 + p*10 + i];
    const float* wq = (const float*)d_in[24];
    const float* wk = (const float*)d_in[25];
    const float* wv = (const float*)d_in[26];
    const float* wo = (const float*)d_in[27];
    const float* bq = (const float*)d_in[28];
    const float* bk = (const float*)d_in[29];
    const float* bv = (const float*)d_in[30];
    const float* bo = (const float*)d_in[31];
    const float* conv_w = (const float*)d_in[32];
    const float* conv_b = (const float*)d_in[33];
    const float* mlp_w1 = (const float*)d_in[34];
    const float* mlp_b1 = (const float*)d_in[35];
    const float* mlp_w2 = (const float*)d_in[36];
    const float* mlp_b2 = (const float*)d_in[37];
    float* out = (float*)d_out;

    const size_t BUF = (size_t)RR*HH;          // 6,144,000 elements
    float* A    = (float*)d_ws;                // h f32
    float* AGG  = A + BUF;                     // agg f32
    _Float16* QF  = (_Float16*)(AGG + BUF);    // Q f16
    _Float16* KF  = QF + BUF;                  // K f16
    _Float16* VF  = KF + BUF;                  // V f16
    _Float16* OF  = VF + BUF;                  // attn out f16
    _Float16* H2F = OF + BUF;                  // sp2 h2 f16
    _Float16* PRE = H2F + BUF;                 // msg layer-1 pre f16
    int*   cnt      = (int*)(PRE + BUF);
    int*   ofs_work = cnt + 2048;
    int*   ssrc     = ofs_work + 2048;
    int*   stgt     = ssrc + EE;
    __bf16* mw2t0   = (__bf16*)(stgt + EE);
    __bf16* mw2t1   = mw2t0 + 2048;
    _Float16* uw1t0 = (_Float16*)(mw2t1 + 2048);
    _Float16* uw1t1 = uw1t0 + 8192;
    _Float16* uw2t0 = uw1t1 + 8192;
    _Float16* uw2t1 = uw2t0 + 4096;
    _Float16* qkvt  = uw2t1 + 4096;
    _Float16* wot   = qkvt + 3*4096;
    _Float16* mw1t0 = wot + 4096;
    _Float16* mw1t1 = mw1t0 + 4096;
    _Float16* upwt  = mw1t1 + 4096;
    _Float16* ZF = (_Float16*)AGG;   // z f16 (13.8 MB) overlays AGG (dead by then)

    const int GT = RR/32;   // 3000 blocks of 64 (32-row MFMA tiles)

    // ---- CSR build + weight prep ----
    hipMemsetAsync(cnt, 0, 2048*sizeof(int), stream);
    k_hist<<<(EE+255)/256, 256, 0, stream>>>(eidx, cnt);
    k_wprep<<<64, 256, 0, stream>>>(
        sp_w[0][2], sp_w[1][2], sp_w[0][6], sp_w[1][6], sp_w[0][8], sp_w[1][8],
        wq, wk, wv, wo, sp_w[0][0], sp_w[1][0], up_w,
        mw2t0, mw2t1, uw1t0, uw1t1, uw2t0, uw2t1, qkvt, wot, mw1t0, mw1t1, upwt);
    k_scan<<<1, 256, 0, stream>>>(cnt, ofs_work);
    k_scatter<<<(EE+255)/256, 256, 0, stream>>>(eidx, ofs_work, ssrc, stgt);

    // 1. fused up-projection + sp1 pre (MFMA)
    k_upre<<<GT, 64, 0, stream>>>(x, upwt, up_b, mw1t0, A, PRE);

    // 2. spatial 1 + fused update/QKV (h2 never materialized; QKV f16)
    hipMemsetAsync(AGG, 0, BUF*sizeof(float), stream);
    k_msg<<<BT*(EE/64), 64, 0, stream>>>(PRE, ssrc, stgt,
        sp_w[0][1], mw2t0, sp_w[0][3], sp_w[0][4], sp_w[0][5], AGG);
    k_updqkv<<<GT, 64, 0, stream>>>(AGG, A,
        uw1t0, sp_w[0][7], uw2t0, sp_w[0][9],
        qkvt, bq, bk, bv, QF, KF, VF);

    // 3. attention (f16 IO) + Wo + sp2 pre
    k_attn2<<<BB*NN, 64, 0, stream>>>(QF, KF, VF, OF);
    k_wopre<<<GT, 64, 0, stream>>>(OF, wot, bo, mw1t1, A, PRE);

    // 4. spatial 2
    hipMemsetAsync(AGG, 0, BUF*sizeof(float), stream);
    k_msg<<<BT*(EE/64), 64, 0, stream>>>(PRE, ssrc, stgt,
        sp_w[1][1], mw2t1, sp_w[1][3], sp_w[1][4], sp_w[1][5], AGG);
    k_updm<<<GT, 64, 0, stream>>>(AGG, A, uw1t1, sp_w[1][7], uw2t1, sp_w[1][9], H2F);

    // 5. conv + MLP head (z f16, overlays AGG)
    k_zbuild<<<(BB*NN*64 + 255)/256, 256, 0, stream>>>(H2F, x, conv_w, conv_b, ZF);
    k_headmlp<<<(BB*HORZ*NN)/16, 256, 0, stream>>>(ZF,
        mlp_w1, mlp_b1, mlp_w2, mlp_b2, out);
}

// Round 14
// 491.856 us; speedup vs baseline: 1.0322x; 1.0322x over previous
//
#include <hip/hip_runtime.h>
#include <math.h>

#define BB 4
#define TT 12
#define NN 2000
#define CC 8
#define HH 64
#define EE 32000
#define NHEADS 8
#define HD 8
#define HORZ 12
#define BT (BB*TT)        // 48
#define RR (BT*NN)        // 96000 rows of H=64

using bf16x8 = __attribute__((ext_vector_type(8))) __bf16;
using f16x8  = __attribute__((ext_vector_type(8))) _Float16;
using f16x4  = __attribute__((ext_vector_type(4))) _Float16;
using f32x4  = __attribute__((ext_vector_type(4))) float;

__device__ __forceinline__ float sigmoidf_(float x){ return 1.0f/(1.0f+__expf(-x)); }
__device__ __forceinline__ float siluf_(float x){ return x/(1.0f+__expf(-x)); }

// ================= CSR build (edges sorted by tgt) =================
__global__ void k_hist(const int* __restrict__ eidx, int* __restrict__ cnt) {
    int e = blockIdx.x*blockDim.x + threadIdx.x;
    if (e < EE) atomicAdd(&cnt[eidx[EE + e]], 1);
}

__global__ __launch_bounds__(256) void k_scan(const int* __restrict__ cnt,
                                              int* __restrict__ ofs_work) {
    __shared__ int part[256];
    int tid = threadIdx.x;
    int local[8]; int s = 0;
    #pragma unroll
    for (int k = 0; k < 8; ++k) {
        int idx = tid*8 + k;
        int v = (idx < NN) ? cnt[idx] : 0;
        local[k] = s; s += v;
    }
    part[tid] = s; __syncthreads();
    for (int off = 1; off < 256; off <<= 1) {
        int v = part[tid];
        int u = (tid >= off) ? part[tid-off] : 0;
        __syncthreads();
        part[tid] = v + u;
        __syncthreads();
    }
    int excl = part[tid] - s;
    #pragma unroll
    for (int k = 0; k < 8; ++k) {
        int idx = tid*8 + k;
        if (idx < NN) ofs_work[idx] = excl + local[k];
    }
}

__global__ void k_scatter(const int* __restrict__ eidx, int* __restrict__ ofs_work,
                          int* __restrict__ ssrc, int* __restrict__ stgt) {
    int e = blockIdx.x*blockDim.x + threadIdx.x;
    if (e >= EE) return;
    int t = eidx[EE + e];
    int pos = atomicAdd(&ofs_work[t], 1);
    ssrc[pos] = eidx[e];
    stgt[pos] = t;
}

// ========== one-shot weight prep: transposed [n][k] low-precision copies ==
__global__ void k_wprep(
    const float* __restrict__ mw2_0, const float* __restrict__ mw2_1,
    const float* __restrict__ uw1_0, const float* __restrict__ uw1_1,
    const float* __restrict__ uw2_0, const float* __restrict__ uw2_1,
    const float* __restrict__ wq, const float* __restrict__ wk,
    const float* __restrict__ wv, const float* __restrict__ wo,
    const float* __restrict__ mw1_0, const float* __restrict__ mw1_1,
    const float* __restrict__ up_w,
    __bf16* __restrict__ mw2t0, __bf16* __restrict__ mw2t1,
    _Float16* __restrict__ uw1t0, _Float16* __restrict__ uw1t1,
    _Float16* __restrict__ uw2t0, _Float16* __restrict__ uw2t1,
    _Float16* __restrict__ qkvt, _Float16* __restrict__ wot,
    _Float16* __restrict__ mw1t0, _Float16* __restrict__ mw1t1,
    _Float16* __restrict__ upwt)
{
    int i = blockIdx.x*blockDim.x + threadIdx.x;
    if (i < 2048) {
        int n = i >> 5, k = i & 31;
        mw2t0[i] = (__bf16)mw2_0[k*64 + n];
        mw2t1[i] = (__bf16)mw2_1[k*64 + n];
        return;
    }
    i -= 2048;
    if (i < 8192) {
        int n = i >> 7, k = i & 127;
        uw1t0[i] = (_Float16)uw1_0[k*64 + n];
        uw1t1[i] = (_Float16)uw1_1[k*64 + n];
        return;
    }
    i -= 8192;
    if (i < 4096) {
        int n = i >> 6, k = i & 63;
        uw2t0[i] = (_Float16)uw2_0[k*64 + n];
        uw2t1[i] = (_Float16)uw2_1[k*64 + n];
        wot[i]   = (_Float16)wo[k*64 + n];
        qkvt[i]        = (_Float16)wq[k*64 + n];
        qkvt[4096 + i] = (_Float16)wk[k*64 + n];
        qkvt[8192 + i] = (_Float16)wv[k*64 + n];
        mw1t0[i] = (_Float16)((n < 32) ? mw1_0[k*32 + n] : mw1_0[(64 + k)*32 + n - 32]);
        mw1t1[i] = (_Float16)((n < 32) ? mw1_1[k*32 + n] : mw1_1[(64 + k)*32 + n - 32]);
        return;
    }
    i -= 4096;
    if (i < 2048) {   // up_w (8x64) -> [n=64][k=32], zero-padded past k=8
        int n = i >> 5, k = i & 31;
        upwt[i] = (k < CC) ? (_Float16)up_w[k*64 + n] : (_Float16)0.0f;
    }
}

// ====== MFMA helpers: 32-row tile per wave, A direct from global f32 ======
__device__ __forceinline__ f16x8 load_a_f16(const float* __restrict__ p) {
    f32x4 lo = *(const f32x4*)p, hi = *(const f32x4*)(p + 4);
    f16x8 v;
    #pragma unroll
    for (int u = 0; u < 4; ++u) { v[u] = (_Float16)lo[u]; v[4+u] = (_Float16)hi[u]; }
    return v;
}

// ------- fused up-projection (MFMA, K=8 padded) + sp1 msg-layer-1 pre ----
__global__ __launch_bounds__(64) void k_upre(
    const float* __restrict__ x, const _Float16* __restrict__ upwt,
    const float* __restrict__ upb, const _Float16* __restrict__ mw1t,
    float* __restrict__ h, _Float16* __restrict__ preB)
{
    __shared__ _Float16 hS[32][72];
    int t = threadIdx.x; int l15 = t & 15, quad = t >> 4;
    size_t R0 = (size_t)blockIdx.x*32;

    f16x8 a[2];
    #pragma unroll
    for (int mi = 0; mi < 2; ++mi) {
        f16x8 v;
        #pragma unroll
        for (int u = 0; u < 8; ++u) v[u] = (_Float16)0.0f;
        if (quad == 0) {
            const float* xr = x + (R0 + 16*mi + l15)*CC;
            f32x4 lo = *(const f32x4*)xr, hi = *(const f32x4*)(xr + 4);
            #pragma unroll
            for (int u = 0; u < 4; ++u) { v[u] = (_Float16)lo[u]; v[4+u] = (_Float16)hi[u]; }
        }
        a[mi] = v;
    }
    f32x4 acc[2][4];
    #pragma unroll
    for (int mi = 0; mi < 2; ++mi)
        #pragma unroll
        for (int ni = 0; ni < 4; ++ni) acc[mi][ni] = (f32x4){0.f,0.f,0.f,0.f};
    #pragma unroll
    for (int ni = 0; ni < 4; ++ni) {
        f16x8 b = *(const f16x8*)&upwt[(16*ni + l15)*32 + quad*8];
        #pragma unroll
        for (int mi = 0; mi < 2; ++mi)
            acc[mi][ni] = __builtin_amdgcn_mfma_f32_16x16x32_f16(a[mi], b, acc[mi][ni], 0,0,0);
    }
    #pragma unroll
    for (int mi = 0; mi < 2; ++mi)
        #pragma unroll
        for (int ni = 0; ni < 4; ++ni) {
            int col = 16*ni + l15;
            float bb = upb[col];
            #pragma unroll
            for (int rg = 0; rg < 4; ++rg) {
                int row = 16*mi + 4*quad + rg;
                float o = fmaxf(acc[mi][ni][rg] + bb, 0.f);
                h[(R0 + row)*HH + col] = o;
                hS[row][col] = (_Float16)o;
            }
        }
    __syncthreads();

    f32x4 acc2[2][4];
    #pragma unroll
    for (int mi = 0; mi < 2; ++mi)
        #pragma unroll
        for (int ni = 0; ni < 4; ++ni) acc2[mi][ni] = (f32x4){0.f,0.f,0.f,0.f};
    #pragma unroll
    for (int kc = 0; kc < 2; ++kc) {
        f16x8 av[2];
        #pragma unroll
        for (int mi = 0; mi < 2; ++mi)
            av[mi] = *(const f16x8*)&hS[16*mi + l15][kc*32 + quad*8];
        #pragma unroll
        for (int ni = 0; ni < 4; ++ni) {
            f16x8 b = *(const f16x8*)&mw1t[(16*ni + l15)*64 + kc*32 + quad*8];
            #pragma unroll
            for (int mi = 0; mi < 2; ++mi)
                acc2[mi][ni] = __builtin_amdgcn_mfma_f32_16x16x32_f16(av[mi], b, acc2[mi][ni], 0,0,0);
        }
    }
    #pragma unroll
    for (int mi = 0; mi < 2; ++mi)
        #pragma unroll
        for (int ni = 0; ni < 4; ++ni) {
            int col = 16*ni + l15;
            #pragma unroll
            for (int rg = 0; rg < 4; ++rg) {
                int row = 16*mi + 4*quad + rg;
                preB[(R0 + row)*HH + col] = (_Float16)acc2[mi][ni][rg];
            }
        }
}

// ------- fused update-MLP(sp1) + QKV: h2 never hits global ---------------
__global__ __launch_bounds__(64) void k_updqkv(
    const float* __restrict__ agg, const float* __restrict__ h,
    const _Float16* __restrict__ w1t, const float* __restrict__ b1,
    const _Float16* __restrict__ w2t, const float* __restrict__ b2,
    const _Float16* __restrict__ qkvt,
    const float* __restrict__ bq, const float* __restrict__ bk,
    const float* __restrict__ bv,
    float* __restrict__ q, float* __restrict__ k, float* __restrict__ v)
{
    __shared__ _Float16 uS[32][72];
    __shared__ _Float16 hS[32][72];
    int t = threadIdx.x; int l15 = t & 15, quad = t >> 4;
    size_t R0 = (size_t)blockIdx.x*32;

    // ---- update layer 1: K=128 ([agg | h]) ----
    f32x4 acc[2][4];
    #pragma unroll
    for (int mi = 0; mi < 2; ++mi)
        #pragma unroll
        for (int ni = 0; ni < 4; ++ni) acc[mi][ni] = (f32x4){0.f,0.f,0.f,0.f};
    #pragma unroll
    for (int kc = 0; kc < 4; ++kc) {
        const float* src = (kc < 2) ? agg : h;
        int colb = (kc & 1)*32 + quad*8;
        f16x8 a[2];
        #pragma unroll
        for (int mi = 0; mi < 2; ++mi)
            a[mi] = load_a_f16(src + (R0 + 16*mi + l15)*HH + colb);
        #pragma unroll
        for (int ni = 0; ni < 4; ++ni) {
            f16x8 b = *(const f16x8*)&w1t[(16*ni + l15)*128 + kc*32 + quad*8];
            #pragma unroll
            for (int mi = 0; mi < 2; ++mi)
                acc[mi][ni] = __builtin_amdgcn_mfma_f32_16x16x32_f16(a[mi], b, acc[mi][ni], 0,0,0);
        }
    }
    #pragma unroll
    for (int mi = 0; mi < 2; ++mi)
        #pragma unroll
        for (int ni = 0; ni < 4; ++ni) {
            int col = 16*ni + l15;
            float bb = b1[col];
            #pragma unroll
            for (int rg = 0; rg < 4; ++rg)
                uS[16*mi + 4*quad + rg][col] = (_Float16)siluf_(acc[mi][ni][rg] + bb);
        }
    __syncthreads();

    // ---- update layer 2: K=64, epilogue -> hS (relu'd h2, f16) ----
    f32x4 acc2[2][4];
    #pragma unroll
    for (int mi = 0; mi < 2; ++mi)
        #pragma unroll
        for (int ni = 0; ni < 4; ++ni) acc2[mi][ni] = (f32x4){0.f,0.f,0.f,0.f};
    #pragma unroll
    for (int kc = 0; kc < 2; ++kc) {
        f16x8 a[2];
        #pragma unroll
        for (int mi = 0; mi < 2; ++mi)
            a[mi] = *(const f16x8*)&uS[16*mi + l15][kc*32 + quad*8];
        #pragma unroll
        for (int ni = 0; ni < 4; ++ni) {
            f16x8 b = *(const f16x8*)&w2t[(16*ni + l15)*64 + kc*32 + quad*8];
            #pragma unroll
            for (int mi = 0; mi < 2; ++mi)
                acc2[mi][ni] = __builtin_amdgcn_mfma_f32_16x16x32_f16(a[mi], b, acc2[mi][ni], 0,0,0);
        }
    }
    #pragma unroll
    for (int mi = 0; mi < 2; ++mi)
        #pragma unroll
        for (int ni = 0; ni < 4; ++ni) {
            int col = 16*ni + l15;
            float bb = b2[col];
            #pragma unroll
            for (int rg = 0; rg < 4; ++rg) {
                int row = 16*mi + 4*quad + rg;
                float o = acc2[mi][ni][rg] + bb + h[(R0 + row)*HH + col];
                hS[row][col] = (_Float16)fmaxf(o, 0.f);
            }
        }
    __syncthreads();

    // ---- QKV from hS (A-frags shared across the 3 projections) ----
    f16x8 a[2][2];
    #pragma unroll
    for (int kc = 0; kc < 2; ++kc)
        #pragma unroll
        for (int mi = 0; mi < 2; ++mi)
            a[kc][mi] = *(const f16x8*)&hS[16*mi + l15][kc*32 + quad*8];

    const float* bias[3] = {bq, bk, bv};
    float* outp[3] = {q, k, v};
    #pragma unroll
    for (int o = 0; o < 3; ++o) {
        f32x4 ac[2][4];
        #pragma unroll
        for (int mi = 0; mi < 2; ++mi)
            #pragma unroll
            for (int ni = 0; ni < 4; ++ni) ac[mi][ni] = (f32x4){0.f,0.f,0.f,0.f};
        #pragma unroll
        for (int kc = 0; kc < 2; ++kc)
            #pragma unroll
            for (int ni = 0; ni < 4; ++ni) {
                f16x8 b = *(const f16x8*)&qkvt[o*4096 + (16*ni + l15)*64 + kc*32 + quad*8];
                #pragma unroll
                for (int mi = 0; mi < 2; ++mi)
                    ac[mi][ni] = __builtin_amdgcn_mfma_f32_16x16x32_f16(a[kc][mi], b, ac[mi][ni], 0,0,0);
            }
        #pragma unroll
        for (int mi = 0; mi < 2; ++mi)
            #pragma unroll
            for (int ni = 0; ni < 4; ++ni) {
                int col = 16*ni + l15;
                float bb = bias[o][col];
                #pragma unroll
                for (int rg = 0; rg < 4; ++rg) {
                    int row = 16*mi + 4*quad + rg;
                    outp[o][(R0 + row)*HH + col] = ac[mi][ni][rg] + bb;
                }
            }
    }
}

// ------- MFMA update MLP (sp2): out = silu([agg,h]@w1+b1)@w2+b2 + h ------
__global__ __launch_bounds__(64) void k_updm(
    const float* __restrict__ agg, const float* __restrict__ h,
    const _Float16* __restrict__ w1t, const float* __restrict__ b1,
    const _Float16* __restrict__ w2t, const float* __restrict__ b2,
    float* __restrict__ out, int do_relu)
{
    __shared__ _Float16 uS[32][72];
    int t = threadIdx.x; int l15 = t & 15, quad = t >> 4;
    size_t R0 = (size_t)blockIdx.x*32;

    f32x4 acc[2][4];
    #pragma unroll
    for (int mi = 0; mi < 2; ++mi)
        #pragma unroll
        for (int ni = 0; ni < 4; ++ni) acc[mi][ni] = (f32x4){0.f,0.f,0.f,0.f};
    #pragma unroll
    for (int kc = 0; kc < 4; ++kc) {
        const float* src = (kc < 2) ? agg : h;
        int colb = (kc & 1)*32 + quad*8;
        f16x8 a[2];
        #pragma unroll
        for (int mi = 0; mi < 2; ++mi)
            a[mi] = load_a_f16(src + (R0 + 16*mi + l15)*HH + colb);
        #pragma unroll
        for (int ni = 0; ni < 4; ++ni) {
            f16x8 b = *(const f16x8*)&w1t[(16*ni + l15)*128 + kc*32 + quad*8];
            #pragma unroll
            for (int mi = 0; mi < 2; ++mi)
                acc[mi][ni] = __builtin_amdgcn_mfma_f32_16x16x32_f16(a[mi], b, acc[mi][ni], 0,0,0);
        }
    }
    #pragma unroll
    for (int mi = 0; mi < 2; ++mi)
        #pragma unroll
        for (int ni = 0; ni < 4; ++ni) {
            int col = 16*ni + l15;
            float bb = b1[col];
            #pragma unroll
            for (int rg = 0; rg < 4; ++rg)
                uS[16*mi + 4*quad + rg][col] = (_Float16)siluf_(acc[mi][ni][rg] + bb);
        }
    __syncthreads();

    f32x4 acc2[2][4];
    #pragma unroll
    for (int mi = 0; mi < 2; ++mi)
        #pragma unroll
        for (int ni = 0; ni < 4; ++ni) acc2[mi][ni] = (f32x4){0.f,0.f,0.f,0.f};
    #pragma unroll
    for (int kc = 0; kc < 2; ++kc) {
        f16x8 a[2];
        #pragma unroll
        for (int mi = 0; mi < 2; ++mi)
            a[mi] = *(const f16x8*)&uS[16*mi + l15][kc*32 + quad*8];
        #pragma unroll
        for (int ni = 0; ni < 4; ++ni) {
            f16x8 b = *(const f16x8*)&w2t[(16*ni + l15)*64 + kc*32 + quad*8];
            #pragma unroll
            for (int mi = 0; mi < 2; ++mi)
                acc2[mi][ni] = __builtin_amdgcn_mfma_f32_16x16x32_f16(a[mi], b, acc2[mi][ni], 0,0,0);
        }
    }
    #pragma unroll
    for (int mi = 0; mi < 2; ++mi)
        #pragma unroll
        for (int ni = 0; ni < 4; ++ni) {
            int col = 16*ni + l15;
            float bb = b2[col];
            #pragma unroll
            for (int rg = 0; rg < 4; ++rg) {
                int row = 16*mi + 4*quad + rg;
                float o = acc2[mi][ni][rg] + bb + h[(R0 + row)*HH + col];
                if (do_relu) o = fmaxf(o, 0.f);
                out[(R0 + row)*HH + col] = o;
            }
        }
}

// ------- MFMA Wo projection + fused sp2 msg-layer-1 precompute -----------
__global__ __launch_bounds__(64) void k_wopre(
    const float* __restrict__ ob, const _Float16* __restrict__ wot,
    const float* __restrict__ bo, const _Float16* __restrict__ mw1t,
    float* __restrict__ aout, _Float16* __restrict__ preB)
{
    __shared__ _Float16 hS[32][72];
    int t = threadIdx.x; int l15 = t & 15, quad = t >> 4;
    size_t R0 = (size_t)blockIdx.x*32;

    f32x4 acc[2][4];
    #pragma unroll
    for (int mi = 0; mi < 2; ++mi)
        #pragma unroll
        for (int ni = 0; ni < 4; ++ni) acc[mi][ni] = (f32x4){0.f,0.f,0.f,0.f};
    #pragma unroll
    for (int kc = 0; kc < 2; ++kc) {
        f16x8 a[2];
        #pragma unroll
        for (int mi = 0; mi < 2; ++mi)
            a[mi] = load_a_f16(ob + (R0 + 16*mi + l15)*HH + kc*32 + quad*8);
        #pragma unroll
        for (int ni = 0; ni < 4; ++ni) {
            f16x8 b = *(const f16x8*)&wot[(16*ni + l15)*64 + kc*32 + quad*8];
            #pragma unroll
            for (int mi = 0; mi < 2; ++mi)
                acc[mi][ni] = __builtin_amdgcn_mfma_f32_16x16x32_f16(a[mi], b, acc[mi][ni], 0,0,0);
        }
    }
    #pragma unroll
    for (int mi = 0; mi < 2; ++mi)
        #pragma unroll
        for (int ni = 0; ni < 4; ++ni) {
            int col = 16*ni + l15;
            float bb = bo[col];
            #pragma unroll
            for (int rg = 0; rg < 4; ++rg) {
                int row = 16*mi + 4*quad + rg;
                float o = acc[mi][ni][rg] + bb;
                aout[(R0 + row)*HH + col] = o;
                hS[row][col] = (_Float16)o;
            }
        }
    __syncthreads();

    f32x4 acc2[2][4];
    #pragma unroll
    for (int mi = 0; mi < 2; ++mi)
        #pragma unroll
        for (int ni = 0; ni < 4; ++ni) acc2[mi][ni] = (f32x4){0.f,0.f,0.f,0.f};
    #pragma unroll
    for (int kc = 0; kc < 2; ++kc) {
        f16x8 a[2];
        #pragma unroll
        for (int mi = 0; mi < 2; ++mi)
            a[mi] = *(const f16x8*)&hS[16*mi + l15][kc*32 + quad*8];
        #pragma unroll
        for (int ni = 0; ni < 4; ++ni) {
            f16x8 b = *(const f16x8*)&mw1t[(16*ni + l15)*64 + kc*32 + quad*8];
            #pragma unroll
            for (int mi = 0; mi < 2; ++mi)
                acc2[mi][ni] = __builtin_amdgcn_mfma_f32_16x16x32_f16(a[mi], b, acc2[mi][ni], 0,0,0);
        }
    }
    #pragma unroll
    for (int mi = 0; mi < 2; ++mi)
        #pragma unroll
        for (int ni = 0; ni < 4; ++ni) {
            int col = 16*ni + l15;
            #pragma unroll
            for (int rg = 0; rg < 4; ++rg) {
                int row = 16*mi + 4*quad + rg;
                preB[(R0 + row)*HH + col] = (_Float16)acc2[mi][ni][rg];
            }
        }
}

// ========== message MLP + gate + indicator-MFMA segmented aggregation =====
// blockIdx = eb*BT + bt -> all 500 windows of a bt land on XCD bt%8
// (FETCH_SIZE 43->7.2 MB measured R10) — keep this mapping.
__global__ __launch_bounds__(64) void k_msg(
    const _Float16* __restrict__ preB, const int* __restrict__ ssrc,
    const int* __restrict__ stgt,
    const float* __restrict__ b1,
    const __bf16* __restrict__ w2t, const float* __restrict__ b2,
    const float* __restrict__ gw, const float* __restrict__ gb,
    float* __restrict__ agg)
{
    int bt = blockIdx.x % BT;          // XCD-local per bt
    int eb = blockIdx.x / BT;
    int t  = threadIdx.x;
    int l15 = t & 15, quad = t >> 4;

    union __align__(16) SM {
        __bf16   ab[64][40];
        _Float16 bs[8][64][8];
    };
    __shared__ SM sm;
    __shared__ int segTgt[64];

    int e0 = eb*64;
    int my_src = ssrc[e0 + t];
    int my_tgt = stgt[e0 + t];

    int prevt = __shfl(my_tgt, (t + 63) & 63);
    bool bnd = (t == 0) || (prevt != my_tgt);
    unsigned long long bm = __ballot(bnd);
    int seg = __builtin_amdgcn_mbcnt_hi((unsigned)(bm >> 32),
              __builtin_amdgcn_mbcnt_lo((unsigned)bm, 0u));
    int nseg = __popcll(bm);
    if (bnd) segTgt[seg] = my_tgt;

    const _Float16* basep = preB + (size_t)bt*NN*HH;
    const _Float16* rT = basep + (size_t)my_tgt*HH;
    const _Float16* rS = basep + (size_t)my_src*HH + 32;
    f16x8 xi[4], xj[4];
    #pragma unroll
    for (int g4 = 0; g4 < 4; ++g4) {
        xi[g4] = *(const f16x8*)&rT[8*g4];
        xj[g4] = *(const f16x8*)&rS[8*g4];
    }
    #pragma unroll
    for (int g4 = 0; g4 < 4; ++g4) {
        bf16x8 v;
        #pragma unroll
        for (int u = 0; u < 8; ++u) {
            float m = (float)xi[g4][u] + (float)xj[g4][u] + b1[8*g4 + u];
            v[u] = (__bf16)siluf_(m);
        }
        ((bf16x8*)&sm.ab[t][0])[g4] = v;
    }

    bf16x8 bfr[4];
    float b2v[4], gwv[4];
    #pragma unroll
    for (int ni = 0; ni < 4; ++ni) {
        bfr[ni] = *(const bf16x8*)&w2t[(16*ni + l15)*32 + quad*8];
        b2v[ni] = b2[16*ni + l15];
        gwv[ni] = gw[16*ni + l15];
    }
    float gb0 = gb[0];

    __syncthreads();

    f32x4 acc[4][4];
    #pragma unroll
    for (int mi = 0; mi < 4; ++mi) {
        bf16x8 af = *(const bf16x8*)&sm.ab[16*mi + l15][quad*8];
        #pragma unroll
        for (int ni = 0; ni < 4; ++ni) {
            f32x4 z = {0.f, 0.f, 0.f, 0.f};
            acc[mi][ni] = __builtin_amdgcn_mfma_f32_16x16x32_bf16(af, bfr[ni], z, 0, 0, 0);
        }
    }
    __syncthreads();

    #pragma unroll
    for (int mi = 0; mi < 4; ++mi) {
        float sv[4][4];
        #pragma unroll
        for (int ni = 0; ni < 4; ++ni)
            #pragma unroll
            for (int rg = 0; rg < 4; ++rg)
                sv[ni][rg] = siluf_(acc[mi][ni][rg] + b2v[ni]);
        float gg[4];
        #pragma unroll
        for (int rg = 0; rg < 4; ++rg) {
            float p = sv[0][rg]*gwv[0] + sv[1][rg]*gwv[1]
                    + sv[2][rg]*gwv[2] + sv[3][rg]*gwv[3];
            p += __shfl_xor(p, 1); p += __shfl_xor(p, 2);
            p += __shfl_xor(p, 4); p += __shfl_xor(p, 8);
            gg[rg] = sigmoidf_(p + gb0);
        }
        int c  = mi >> 1;
        int qb = 2*(mi & 1) + (quad >> 1);
        int j0 = 4*(quad & 1);
        #pragma unroll
        for (int ni = 0; ni < 4; ++ni) {
            f16x4 pk;
            #pragma unroll
            for (int rg = 0; rg < 4; ++rg) pk[rg] = (_Float16)(sv[ni][rg]*gg[rg]);
            *(f16x4*)&sm.bs[c*4 + ni][16*qb + l15][j0] = pk;
        }
    }
    __syncthreads();

    f16x8 bfrag[2][4];
    #pragma unroll
    for (int c = 0; c < 2; ++c)
        #pragma unroll
        for (int ni = 0; ni < 4; ++ni)
            bfrag[c][ni] = *(const f16x8*)&sm.bs[c*4 + ni][t][0];

    float* ap = agg + (size_t)bt*NN*HH;
    for (int g0 = 0; g0 < nseg; g0 += 16) {
        f16x8 ind[2];
        #pragma unroll
        for (int c = 0; c < 2; ++c) {
            #pragma unroll
            for (int j = 0; j < 8; ++j) {
                int sj = __shfl(seg, 32*c + 8*quad + j);
                ind[c][j] = (sj == g0 + l15) ? (_Float16)1.0f : (_Float16)0.0f;
            }
        }
        f32x4 av[4];
        #pragma unroll
        for (int ni = 0; ni < 4; ++ni) {
            f32x4 z = {0.f, 0.f, 0.f, 0.f};
            av[ni] = __builtin_amdgcn_mfma_f32_16x16x32_f16(ind[0], bfrag[0][ni], z, 0, 0, 0);
            av[ni] = __builtin_amdgcn_mfma_f32_16x16x32_f16(ind[1], bfrag[1][ni], av[ni], 0, 0, 0);
        }
        #pragma unroll
        for (int rg = 0; rg < 4; ++rg) {
            int s = g0 + 4*quad + rg;
            if (s < nseg) {
                int tn = segTgt[s];
                #pragma unroll
                for (int ni = 0; ni < 4; ++ni)
                    atomicAdd(&ap[(size_t)tn*HH + 16*ni + l15], av[ni][rg]);
            }
        }
    }
}

// ---------------- temporal attention: wave per (b,n), LDS-staged ----------
__global__ __launch_bounds__(64) void k_attn2(
    const float* __restrict__ q, const float* __restrict__ k,
    const float* __restrict__ v, float* __restrict__ o)
{
    __shared__ float Qs[TT][68], Ks[TT][68], Vs[TT][68], Os[TT][68];
    int p = blockIdx.x;
    int b = p / NN, n = p % NN;
    int j = threadIdx.x;
    const size_t stride = (size_t)NN*HH;
    const size_t base0  = ((size_t)(b*TT)*NN + n)*HH;

    #pragma unroll
    for (int t = 0; t < TT; ++t) {
        size_t off = base0 + (size_t)t*stride + j;
        Qs[t][j] = q[off];
        Ks[t][j] = k[off];
        Vs[t][j] = v[off];
    }
    __syncthreads();

    #pragma unroll
    for (int half = 0; half < 2; ++half) {
        if (j < 48) {
            int head = half*4 + j/12;
            int s    = j % 12;
            f32x4 qv0 = *(const f32x4*)&Qs[s][head*8];
            f32x4 qv1 = *(const f32x4*)&Qs[s][head*8 + 4];
            float sc[TT]; float mx = -1e30f;
            #pragma unroll
            for (int t = 0; t < TT; ++t) {
                f32x4 k0 = *(const f32x4*)&Ks[t][head*8];
                f32x4 k1 = *(const f32x4*)&Ks[t][head*8 + 4];
                float a = qv0[0]*k0[0] + qv0[1]*k0[1] + qv0[2]*k0[2] + qv0[3]*k0[3]
                        + qv1[0]*k1[0] + qv1[1]*k1[1] + qv1[2]*k1[2] + qv1[3]*k1[3];
                a *= 0.35355339059327373f;
                sc[t] = a; mx = fmaxf(mx, a);
            }
            float sum = 0.f;
            #pragma unroll
            for (int t = 0; t < TT; ++t) { sc[t] = __expf(sc[t]-mx); sum += sc[t]; }
            float inv = 1.0f/sum;
            f32x4 o0 = {0.f,0.f,0.f,0.f}, o1 = {0.f,0.f,0.f,0.f};
            #pragma unroll
            for (int t = 0; t < TT; ++t) {
                float a = sc[t]*inv;
                f32x4 v0 = *(const f32x4*)&Vs[t][head*8];
                f32x4 v1 = *(const f32x4*)&Vs[t][head*8 + 4];
                o0[0]+=a*v0[0]; o0[1]+=a*v0[1]; o0[2]+=a*v0[2]; o0[3]+=a*v0[3];
                o1[0]+=a*v1[0]; o1[1]+=a*v1[1]; o1[2]+=a*v1[2]; o1[3]+=a*v1[3];
            }
            *(f32x4*)&Os[s][head*8]     = o0;
            *(f32x4*)&Os[s][head*8 + 4] = o1;
        }
    }
    __syncthreads();

    #pragma unroll
    for (int t = 0; t < TT; ++t)
        o[base0 + (size_t)t*stride + j] = Os[t][j];
}

// ---------------- conv head stage 1: z[b,hor,n,0:72] ----------------------
__global__ __launch_bounds__(256) void k_zbuild(
    const float* __restrict__ h, const float* __restrict__ x,
    const float* __restrict__ cw, const float* __restrict__ cb,
    float* __restrict__ z)
{
    int gid = blockIdx.x*blockDim.x + threadIdx.x;
    int p = gid >> 6;
    int j = gid & 63;
    if (p >= BB*NN) return;
    p = __builtin_amdgcn_readfirstlane(p);
    int b = p / NN, n = p % NN;

    float hv[TT];
    #pragma unroll
    for (int t = 0; t < TT; ++t)
        hv[t] = h[((size_t)(b*TT + t)*NN + n)*HH + j];
    float xv[TT];
    if (j < CC) {
        #pragma unroll
        for (int t = 0; t < TT; ++t)
            xv[t] = x[((size_t)(b*TT + t)*NN + n)*CC + j];
    }

    #pragma unroll
    for (int hor = 0; hor < HORZ; ++hor) {
        float cbv = cb[hor];
        float zh = cbv, zx = cbv;
        #pragma unroll
        for (int t = 0; t < TT; ++t) {
            float w = cw[hor*TT + t];
            zh += w*hv[t];
            if (j < CC) zx += w*xv[t];
        }
        size_t row = (size_t)(b*HORZ + hor)*NN + n;
        z[row*72 + j] = zh;
        if (j < CC) z[row*72 + 64 + j] = zx;
    }
}

// ---------------- conv head stage 2: out = relu(z@w1+b1)@w2+b2 ------------
__global__ __launch_bounds__(256) void k_headmlp(
    const float* __restrict__ z,
    const float* __restrict__ w1, const float* __restrict__ b1,
    const float* __restrict__ w2, const float* __restrict__ b2,
    float* __restrict__ out)
{
    __shared__ float U[4][4][65];
    int gid = blockIdx.x*blockDim.x + threadIdx.x;
    int wv_ = gid >> 6; int j = gid & 63;
    int wl = threadIdx.x >> 6;
    int r0 = wv_*4;
    r0 = __builtin_amdgcn_readfirstlane(r0);
    const float* zr = z + (size_t)r0*72;
    float bj = b1[j];
    float a0=bj,a1=bj,a2=bj,a3=bj;
    #pragma unroll 8
    for (int c = 0; c < 72; ++c) {
        float wc = w1[c*64 + j];
        a0 += zr[c]*wc; a1 += zr[72+c]*wc; a2 += zr[144+c]*wc; a3 += zr[216+c]*wc;
    }
    U[wl][0][j] = fmaxf(a0, 0.f);
    U[wl][1][j] = fmaxf(a1, 0.f);
    U[wl][2][j] = fmaxf(a2, 0.f);
    U[wl][3][j] = fmaxf(a3, 0.f);
    __syncthreads();

    if (j < 32) {
        int r = j >> 3, c = j & 7;
        float o = b2[c];
        #pragma unroll 8
        for (int k = 0; k < 64; ++k)
            o += U[wl][r][k] * w2[k*8 + c];
        out[(size_t)(r0 + r)*CC + c] = o;
    }
}

extern "C" void kernel_launch(void* const* d_in, const int* in_sizes, int n_in,
                              void* d_out, int out_size, void* d_ws, size_t ws_size,
                              hipStream_t stream) {
    const float* x    = (const float*)d_in[0];
    const int*   eidx = (const int*)d_in[1];
    const float* up_w = (const float*)d_in[2];
    const float* up_b = (const float*)d_in[3];
    const float* sp_w[2][10];
    for (int p = 0; p < 2; ++p)
        for (int i = 0; i < 10; ++i)
            sp_w[p][i] = (const float*)d_in[4 + p*10 + i];
    const float* wq = (const float*)d_in[24];
    const float* wk = (const float*)d_in[25];
    const float* wv = (const float*)d_in[26];
    const float* wo = (const float*)d_in[27];
    const float* bq = (const float*)d_in[28];
    const float* bk = (const float*)d_in[29];
    const float* bv = (const float*)d_in[30];
    const float* bo = (const float*)d_in[31];
    const float* conv_w = (const float*)d_in[32];
    const float* conv_b = (const float*)d_in[33];
    const float* mlp_w1 = (const float*)d_in[34];
    const float* mlp_b1 = (const float*)d_in[35];
    const float* mlp_w2 = (const float*)d_in[36];
    const float* mlp_b2 = (const float*)d_in[37];
    float* out = (float*)d_out;

    const size_t BUF = (size_t)RR*HH;      // 6,144,000 elements
    float* A    = (float*)d_ws;            // h / Q
    float* Bb   = A   + BUF;               // h2 (sp2 only)
    float* AGG  = Bb  + BUF;               // agg / K
    float* Vb   = AGG + BUF;               // V
    float* Ob   = Vb  + BUF;               // attn out
    _Float16* PRE = (_Float16*)(Ob + BUF); // first-layer precompute (f16)
    int*   cnt      = (int*)(PRE + BUF);
    int*   ofs_work = cnt + 2048;
    int*   ssrc     = ofs_work + 2048;
    int*   stgt     = ssrc + EE;
    __bf16* mw2t0   = (__bf16*)(stgt + EE);
    __bf16* mw2t1   = mw2t0 + 2048;
    _Float16* uw1t0 = (_Float16*)(mw2t1 + 2048);
    _Float16* uw1t1 = uw1t0 + 8192;
    _Float16* uw2t0 = uw1t1 + 8192;
    _Float16* uw2t1 = uw2t0 + 4096;
    _Float16* qkvt  = uw2t1 + 4096;
    _Float16* wot   = qkvt + 3*4096;
    _Float16* mw1t0 = wot + 4096;
    _Float16* mw1t1 = mw1t0 + 4096;
    _Float16* upwt  = mw1t1 + 4096;   // 2048
    float* Z = AGG;   // z (27.6 MB) overlays AGG+Vb (dead by then)

    const int GT = RR/32;   // 3000 blocks of 64 (32-row MFMA tiles)

    // ---- CSR build + weight prep ----
    hipMemsetAsync(cnt, 0, 2048*sizeof(int), stream);
    k_hist<<<(EE+255)/256, 256, 0, stream>>>(eidx, cnt);
    k_wprep<<<64, 256, 0, stream>>>(
        sp_w[0][2], sp_w[1][2], sp_w[0][6], sp_w[1][6], sp_w[0][8], sp_w[1][8],
        wq, wk, wv, wo, sp_w[0][0], sp_w[1][0], up_w,
        mw2t0, mw2t1, uw1t0, uw1t1, uw2t0, uw2t1, qkvt, wot, mw1t0, mw1t1, upwt);
    k_scan<<<1, 256, 0, stream>>>(cnt, ofs_work);
    k_scatter<<<(EE+255)/256, 256, 0, stream>>>(eidx, ofs_work, ssrc, stgt);

    // 1. fused up-projection + sp1 pre (MFMA)
    k_upre<<<GT, 64, 0, stream>>>(x, upwt, up_b, mw1t0, A, PRE);

    // 2. spatial 1 + fused update/QKV (h2 never materialized)
    hipMemsetAsync(AGG, 0, BUF*sizeof(float), stream);
    k_msg<<<BT*(EE/64), 64, 0, stream>>>(PRE, ssrc, stgt,
        sp_w[0][1], mw2t0, sp_w[0][3], sp_w[0][4], sp_w[0][5], AGG);
    k_updqkv<<<GT, 64, 0, stream>>>(AGG, A,
        uw1t0, sp_w[0][7], uw2t0, sp_w[0][9],
        qkvt, bq, bk, bv, A, AGG, Vb);

    // 3. attention + Wo + sp2 pre
    k_attn2<<<BB*NN, 64, 0, stream>>>(A, AGG, Vb, Ob);
    k_wopre<<<GT, 64, 0, stream>>>(Ob, wot, bo, mw1t1, A, PRE);

    // 4. spatial 2
    hipMemsetAsync(AGG, 0, BUF*sizeof(float), stream);
    k_msg<<<BT*(EE/64), 64, 0, stream>>>(PRE, ssrc, stgt,
        sp_w[1][1], mw2t1, sp_w[1][3], sp_w[1][4], sp_w[1][5], AGG);
    k_updm<<<GT, 64, 0, stream>>>(AGG, A, uw1t1, sp_w[1][7], uw2t1, sp_w[1][9], Bb, 1);

    // 5. conv + MLP head
    k_zbuild<<<(BB*NN*64 + 255)/256, 256, 0, stream>>>(Bb, x, conv_w, conv_b, Z);
    k_headmlp<<<(BB*HORZ*NN)/16, 256, 0, stream>>>(Z,
        mlp_w1, mlp_b1, mlp_w2, mlp_b2, out);
}